// Round 4
// baseline (161.057 us; speedup 1.0000x reference)
//
#include <hip/hip_runtime.h>

typedef __attribute__((ext_vector_type(4))) float f32x4;
typedef __attribute__((ext_vector_type(8))) short bf16x8;

__device__ __forceinline__ short f2bf(float f) {
    union { float f; unsigned u; } v; v.f = f;
    unsigned u = v.u + 0x7FFFu + ((v.u >> 16) & 1u);   // RNE
    return (short)(u >> 16);
}
__device__ __forceinline__ int pack_bf2(float a, float b) {
    union { float f; unsigned u; } ua, ub; ua.f = a; ub.f = b;
    unsigned x = ua.u + 0x8000u, y = ub.u + 0x8000u;   // round half-up
    return (int)__builtin_amdgcn_perm(y, x, 0x07060302u);
}
__device__ __forceinline__ float bflo(int p) {
    union { int i; float f; } v; v.i = p << 16; return v.f;
}
__device__ __forceinline__ float bfhi(int p) {
    union { int i; float f; } v; v.i = p & 0xffff0000; return v.f;
}

// ---------------------------------------------------------------------------
// Prep (16 blocks x 256): emits MFMA-ready fragments.
//  AbP16: per c, 512 frags of 8 bf16: frag f=(rt*2+kc)*64+L holds
//         A_c[pi(rt*16+(L&15))][32kc+8(L>>4)+j]  (16x16x32 A-op layout)
//  Bb16 : bias GEMV A-op, rows=comps: -2*(A_c m_c)[32kc+8q+j]
//  kscal: m^T A m
// ---------------------------------------------------------------------------
__global__ void gmm_prep(const float* __restrict__ Ainv,
                         const float* __restrict__ means,
                         short* __restrict__ AbP16,
                         short* __restrict__ Bb16,
                         float* __restrict__ kscal) {
    __shared__ float sA[64 * 68];
    __shared__ float sm[64];
    __shared__ float sb[64];
    const int c = blockIdx.x, t = threadIdx.x;
    const float* A = Ainv + c * 4096;
    #pragma unroll
    for (int i = 0; i < 4; ++i) {
        int flat = i * 1024 + t * 4;
        int r = flat >> 6, col = flat & 63;
        *(f32x4*)&sA[r * 68 + col] = *(const f32x4*)(A + flat);
    }
    if (t < 64) sm[t] = means[c * 64 + t];
    __syncthreads();
    {   // b[j] = A[j,:].m  (4 lanes per row)
        int j = t >> 2, seg = t & 3;
        float p = 0.f;
        #pragma unroll
        for (int k = 0; k < 16; ++k) p += sA[j * 68 + seg * 16 + k] * sm[seg * 16 + k];
        p += __shfl_xor(p, 1, 64); p += __shfl_xor(p, 2, 64);
        if ((t & 3) == 0) sb[j] = p;
    }
    __syncthreads();
    if (t < 64) {
        float km = sm[t] * sb[t];
        #pragma unroll
        for (int off = 32; off >= 1; off >>= 1) km += __shfl_xor(km, off, 64);
        if (t == 0) kscal[c] = km;
    }
    #pragma unroll
    for (int rep = 0; rep < 2; ++rep) {     // permuted A fragments
        int f = rep * 256 + t;
        int rt = f >> 7, kc = (f >> 6) & 1, L = f & 63;
        int ln = L & 15, q = L >> 4;
        int pj = (rt >> 1) * 32 + 8 * (ln >> 2) + 4 * (rt & 1) + (ln & 3);
        const float* src = &sA[pj * 68 + 32 * kc + 8 * q];
        bf16x8 v;
        #pragma unroll
        for (int j = 0; j < 8; ++j) v[j] = f2bf(src[j]);
        *(bf16x8*)(AbP16 + c * 4096 + f * 8) = v;
    }
    if (t < 8) {                            // bias GEMV frags (row = comp c)
        int kc = t >> 2, q = t & 3, L = q * 16 + c;
        bf16x8 v;
        #pragma unroll
        for (int j = 0; j < 8; ++j) v[j] = f2bf(-2.f * sb[32 * kc + 8 * q + j]);
        *(bf16x8*)(Bb16 + kc * 512 + L * 8) = v;
    }
}

// ---------------------------------------------------------------------------
// Main (1024 blocks x 256): wave w owns 64 samples (4 tiles of 16), x in regs
// for the whole kernel. A staged in LDS in 4-component rounds (32 KB, reg-
// prefetched); each 8 KB A-frag read serves 4 tiles. Linear+const term via a
// 2-MFMA GEMV per tile with kscal folded into C-init.
// ---------------------------------------------------------------------------
__global__ __launch_bounds__(256, 3) void gmm_main(
    const float* __restrict__ X,
    const float* __restrict__ weights,
    const short* __restrict__ AbP16,
    const short* __restrict__ Bb16,
    const float* __restrict__ kscal,
    float* __restrict__ out) {

    __shared__ short sAb[16384];            // 32 KB: one 4-comp group

    const int tid = threadIdx.x;
    const int lane = tid & 63, w = tid >> 6;
    const int q = lane >> 4, ln = lane & 15;
    const int base = blockIdx.x * 256 + w * 64;
    const f32x4 zero4 = {0.f, 0.f, 0.f, 0.f};

    // ---- x -> bf16 B-fragments (persistent; also the epilogue multiplier) ----
    union BFrag { bf16x8 v; int i[4]; };
    BFrag xb[4][2];
    #pragma unroll
    for (int t = 0; t < 4; ++t) {
        const float* xr = X + (size_t)(base + t * 16 + ln) * 64 + 8 * q;
        #pragma unroll
        for (int kc = 0; kc < 2; ++kc) {
            f32x4 a = *(const f32x4*)(xr + 32 * kc);
            f32x4 b = *(const f32x4*)(xr + 32 * kc + 4);
            xb[t][kc].i[0] = pack_bf2(a[0], a[1]);
            xb[t][kc].i[1] = pack_bf2(a[2], a[3]);
            xb[t][kc].i[2] = pack_bf2(b[0], b[1]);
            xb[t][kc].i[3] = pack_bf2(b[2], b[3]);
        }
    }

    // ---- linear + const term: lin[t][r] = kscal[4q+r] - 2 b_{4q+r}.x ----
    f32x4 kw = *(const f32x4*)(kscal + 4 * q);
    f32x4 wc4 = *(const f32x4*)(weights + 4 * q);
    bf16x8 bb0 = *(const bf16x8*)(Bb16 + lane * 8);
    bf16x8 bb1 = *(const bf16x8*)(Bb16 + 512 + lane * 8);
    f32x4 lin[4];
    #pragma unroll
    for (int t = 0; t < 4; ++t) {
        lin[t] = __builtin_amdgcn_mfma_f32_16x16x32_bf16(bb0, xb[t][0].v, kw, 0, 0, 0);
        lin[t] = __builtin_amdgcn_mfma_f32_16x16x32_bf16(bb1, xb[t][1].v, lin[t], 0, 0, 0);
    }

    // ---- group 0 prefetch (8 int4/thread, stride-interleaved) ----
    int4 pf[8];
    #pragma unroll
    for (int i = 0; i < 8; ++i)
        pf[i] = ((const int4*)AbP16)[i * 256 + tid];

    float slog[4] = {0.f, 0.f, 0.f, 0.f};

    #pragma unroll 1
    for (int g = 0; g < 4; ++g) {
        #pragma unroll
        for (int i = 0; i < 8; ++i)
            ((int4*)sAb)[i * 256 + tid] = pf[i];
        __syncthreads();
        if (g < 3) {
            const int4* src = (const int4*)(AbP16 + (g + 1) * 16384);
            #pragma unroll
            for (int i = 0; i < 8; ++i) pf[i] = src[i * 256 + tid];
        }

        #pragma unroll
        for (int cl = 0; cl < 4; ++cl) {
            bf16x8 af[4][2];
            #pragma unroll
            for (int rt = 0; rt < 4; ++rt)
                #pragma unroll
                for (int kc = 0; kc < 2; ++kc)
                    af[rt][kc] = *(const bf16x8*)&sAb[((cl * 4 + rt) * 2 + kc) * 512 + lane * 8];

            #pragma unroll
            for (int t = 0; t < 4; ++t) {
                float dp = 0.f;
                #pragma unroll
                for (int rt = 0; rt < 4; ++rt) {
                    f32x4 acc = __builtin_amdgcn_mfma_f32_16x16x32_bf16(
                        af[rt][0], xb[t][0].v, zero4, 0, 0, 0);
                    acc = __builtin_amdgcn_mfma_f32_16x16x32_bf16(
                        af[rt][1], xb[t][1].v, acc, 0, 0, 0);
                    int pa = xb[t][rt >> 1].i[(rt & 1) * 2];
                    int pb = xb[t][rt >> 1].i[(rt & 1) * 2 + 1];
                    dp += acc[0] * bflo(pa) + acc[1] * bfhi(pa)
                        + acc[2] * bflo(pb) + acc[3] * bfhi(pb);
                }
                dp += __shfl_xor(dp, 16, 64);
                dp += __shfl_xor(dp, 32, 64);
                if (q == g) {               // quad g owns comps 4g..4g+3
                    float d = fmaxf(dp + lin[t][cl], 1e-30f);
                    slog[t] = fmaf(wc4[cl], __builtin_amdgcn_logf(d), slog[t]);
                }
            }
        }
        __syncthreads();
    }

    #pragma unroll
    for (int t = 0; t < 4; ++t) {
        float tot = slog[t];
        tot += __shfl_xor(tot, 16, 64);
        tot += __shfl_xor(tot, 32, 64);
        if (q == 0) out[base + t * 16 + ln] = __builtin_amdgcn_exp2f(tot);
    }
}

extern "C" void kernel_launch(void* const* d_in, const int* in_sizes, int n_in,
                              void* d_out, int out_size, void* d_ws, size_t ws_size,
                              hipStream_t stream) {
    const float* X       = (const float*)d_in[0];
    const float* Ainv    = (const float*)d_in[1];
    const float* means   = (const float*)d_in[2];
    const float* weights = (const float*)d_in[3];
    float* out = (float*)d_out;
    const int N = in_sizes[0] / 64;

    short* AbP16 = (short*)d_ws;                       // 131072 B
    short* Bb16  = (short*)((char*)d_ws + 131072);     // 2048 B
    float* kscal = (float*)((char*)d_ws + 133120);     // 64 B

    gmm_prep<<<dim3(16), dim3(256), 0, stream>>>(Ainv, means, AbP16, Bb16, kscal);
    gmm_main<<<dim3(N / 256), dim3(256), 0, stream>>>(X, weights, AbP16, Bb16, kscal, out);
}